// Round 11
// baseline (100.029 us; speedup 1.0000x reference)
//
#include <hip/hip_runtime.h>
#include <hip/hip_bf16.h>
#include <cstdint>

#define DEV static __device__ __forceinline__

typedef float        v4f __attribute__((ext_vector_type(4)));
typedef float        v2f __attribute__((ext_vector_type(2)));
typedef short        v8s __attribute__((ext_vector_type(8)));
typedef unsigned int v4u __attribute__((ext_vector_type(4)));
typedef _Float16     v8h __attribute__((ext_vector_type(8)));

static constexpr int N_ENT = 100000;
static constexpr int BATCH = 4096;

DEV unsigned short f2bf(float f) {
    __hip_bfloat16 h = __float2bfloat16(f);
    return __builtin_bit_cast(unsigned short, h);
}
DEV unsigned int pkbf(float lo, float hi) {
    return (unsigned)f2bf(lo) | ((unsigned)f2bf(hi) << 16);
}
DEV float bflo(unsigned int w) { return __uint_as_float(w << 16); }
DEV float bfhi(unsigned int w) { return __uint_as_float(w & 0xffff0000u); }
DEV v2f up2(unsigned int w) { return (v2f){bflo(w), bfhi(w)}; }
DEV unsigned int pkh(float a, float b) {   // f32x2 -> packed f16x2 (RTZ)
    return __builtin_bit_cast(unsigned int, __builtin_amdgcn_cvt_pkrtz(a, b));
}
DEV float fexp(float x) { return __builtin_amdgcn_exp2f(1.44269504f * x); }  // e^x
DEV float frcp(float x) { return __builtin_amdgcn_rcpf(x); }

// ---------------- K0: R1h = fp16(rel @ W1[64:]); W2ph fp16 / W1p bf16 MFMA frag layout
__global__ void k0_prep(const float* __restrict__ rel, const float* __restrict__ W1,
                        const float* __restrict__ W2,
                        unsigned short* __restrict__ R1h, unsigned short* __restrict__ W2ph,
                        unsigned short* __restrict__ W1p)
{
    const int gid = blockIdx.x * 256 + threadIdx.x;
    if (gid < 1024) {
        const int r = gid >> 5, jp = gid & 31;
        float d0 = 0.f, d1 = 0.f;
        #pragma unroll 8
        for (int k = 0; k < 64; ++k) {
            const float rv = rel[r * 64 + k];
            d0 += rv * W1[(64 + k) * 64 + 2 * jp];
            d1 += rv * W1[(64 + k) * 64 + 2 * jp + 1];
        }
        ((unsigned int*)R1h)[r * 32 + jp] = pkh(d0, d1);
    } else if (gid < 1024 + 4096) {
        // Wp[((kk*4+tn)*64 + l)*8 + i] = f16( W2[(32kk + 8*(l>>4) + i)][16tn + (l&15)] )
        const int f = gid - 1024;
        const int i = f & 7, l = (f >> 3) & 63;
        const int tn = (f >> 9) & 3, kk = f >> 11;
        const _Float16 hv = (_Float16)W2[(32 * kk + 8 * (l >> 4) + i) * 64 + 16 * tn + (l & 15)];
        W2ph[f] = __builtin_bit_cast(unsigned short, hv);
    } else if (gid < 1024 + 8192) {
        const int f = gid - 5120;
        const int i = f & 7, l = (f >> 3) & 63;
        const int tn = (f >> 9) & 3, kk = f >> 11;
        W1p[f] = f2bf(W1[(32 * kk + 8 * (l >> 4) + i) * 64 + 16 * tn + (l & 15)]);
    }
}

// ---------------- K1: transposed MFMA: E1h[e][j] fp16 = emb[e] @ W1[:64]; E0 = bf16(emb)
__global__ void __launch_bounds__(256) k1_e1(const float* __restrict__ emb,
                                             const unsigned short* __restrict__ W1p,
                                             unsigned short* __restrict__ E1h,
                                             unsigned short* __restrict__ E0)
{
    const int lane = threadIdx.x & 63;
    const int q = lane & 15, g = lane >> 4;
    const int wid = blockIdx.x * 4 + (threadIdx.x >> 6);
    const int e0 = wid * 16;
    if (e0 >= N_ENT) return;

    v8s bf[2];
    #pragma unroll
    for (int kk = 0; kk < 2; ++kk) {
        const float* p = emb + (size_t)(e0 + q) * 64 + 32 * kk + 8 * g;
        const v4f x = *(const v4f*)p;
        const v4f y = *(const v4f*)(p + 4);
        v4u pk;
        pk[0] = pkbf(x[0], x[1]); pk[1] = pkbf(x[2], x[3]);
        pk[2] = pkbf(y[0], y[1]); pk[3] = pkbf(y[2], y[3]);
        bf[kk] = __builtin_bit_cast(v8s, pk);
        *(v4u*)(E0 + (size_t)(e0 + q) * 64 + 32 * kk + 8 * g) = pk;
    }

    // D = W1^T-block * emb-block: lane(q,g) reg i = E1[e0+q][16*tile + 4g + i]
    v4f acc[4];
    #pragma unroll
    for (int tile = 0; tile < 4; ++tile) acc[tile] = (v4f){0.f, 0.f, 0.f, 0.f};
    #pragma unroll
    for (int kk = 0; kk < 2; ++kk)
        #pragma unroll
        for (int tile = 0; tile < 4; ++tile) {
            const v8s w1f = *(const v8s*)(W1p + ((kk * 4 + tile) * 64 + lane) * 8);
            acc[tile] = __builtin_amdgcn_mfma_f32_16x16x32_bf16(w1f, bf[kk], acc[tile], 0, 0, 0);
        }
    #pragma unroll
    for (int tile = 0; tile < 4; ++tile) {
        unsigned int u[2];
        u[0] = pkh(acc[tile][0], acc[tile][1]);
        u[1] = pkh(acc[tile][2], acc[tile][3]);
        *(unsigned long long*)(E1h + (size_t)(e0 + q) * 64 + 16 * tile + 4 * g) =
            ((unsigned long long)u[1] << 32) | u[0];
    }
}

// ---------------- K2: 2 batch elems/block, 8 waves; wave = one combo of one elem
__global__ void __launch_bounds__(512) k2_fused(
    const int* __restrict__ items,
    const int* __restrict__ user_h, const int* __restrict__ user_r, const int* __restrict__ user_t,
    const int* __restrict__ item_h, const int* __restrict__ item_r, const int* __restrict__ item_t,
    const float* __restrict__ emb, const unsigned short* __restrict__ E0,
    const unsigned short* __restrict__ E1h,
    const unsigned short* __restrict__ R1h, const unsigned short* __restrict__ W2ph,
    const float* __restrict__ W3, float* __restrict__ out)
{
    __shared__ float ws_w[8][64];   // softmax weights (wave-private exchange, no barrier)
    __shared__ float att_s[8][64];  // per-wave attention output
    __shared__ float mp[8][64];     // per-wave mean partials

    const int lane  = threadIdx.x & 63;
    const int w     = threadIdx.x >> 6;     // 0..7
    const int elem  = w >> 2;               // 0..1
    const int combo = w & 3;                // 0:uL0 1:uL1 2:iL0 3:iL1
    const int layer = combo & 1;
    const int side  = combo >> 1, half = combo & 1;
    const int b     = blockIdx.x * 2 + elem;
    const int* Hp; const int* Rp; const int* Tp;
    if (combo < 2) { Hp = user_h; Rp = user_r; Tp = user_t; }
    else           { Hp = item_h; Rp = item_r; Tp = item_t; }
    const int base = (layer * BATCH + b) * 64;
    const int* H0p = (side ? item_h : user_h) + b * 64;

    const int q = lane & 15, g = lane >> 4;
    const int sub = lane & 7, grp = lane >> 3;

    // ---- indices
    int hidx[4], ridx[4];
    #pragma unroll
    for (int tm = 0; tm < 4; ++tm) {
        hidx[tm] = Hp[base + 16 * tm + q];
        ridx[tm] = Rp[base + 16 * tm + q];
    }
    const int tv = Tp[base + lane];
    int midx[4];
    #pragma unroll
    for (int it = 0; it < 4; ++it) midx[it] = H0p[32 * half + 8 * it + grp];

    // ---- gathers (compiler schedules; r3-proven structure)
    v4u ev[4][2], rv[4][2];
    #pragma unroll
    for (int tm = 0; tm < 4; ++tm)
        #pragma unroll
        for (int kk = 0; kk < 2; ++kk) {
            ev[tm][kk] = *(const v4u*)(E1h + (size_t)hidx[tm] * 64 + 32 * kk + 8 * g);
            rv[tm][kk] = *(const v4u*)(R1h + (size_t)ridx[tm] * 64 + 32 * kk + 8 * g);
        }
    v4u e0v[8];
    #pragma unroll
    for (int it = 0; it < 8; ++it) {
        const int tr = __shfl(tv, 8 * it + grp);
        e0v[it] = *(const v4u*)(E0 + (size_t)tr * 64 + sub * 8);
    }
    v4u m0v[4];
    #pragma unroll
    for (int it = 0; it < 4; ++it)
        m0v[it] = *(const v4u*)(E0 + (size_t)midx[it] * 64 + sub * 8);

    float w3v[4];
    #pragma unroll
    for (int tn = 0; tn < 4; ++tn) w3v[tn] = W3[16 * tn + q];
    v8h bfr[2][4];
    #pragma unroll
    for (int kk = 0; kk < 2; ++kk)
        #pragma unroll
        for (int tn = 0; tn < 4; ++tn)
            bfr[kk][tn] = __builtin_bit_cast(v8h, *(const v4u*)(W2ph + ((kk * 4 + tn) * 64 + lane) * 8));

    // ---- MFMA: af = max(e1+r1, 0) in packed fp16 (v_pk_add_f16 + v_pk_max_f16)
    float p[4][4];
    const v8h zz = {};
    #pragma unroll
    for (int tm = 0; tm < 4; ++tm) {
        v4f a4[4];
        #pragma unroll
        for (int tn = 0; tn < 4; ++tn) a4[tn] = (v4f){0.f, 0.f, 0.f, 0.f};
        #pragma unroll
        for (int kk = 0; kk < 2; ++kk) {
            const v8h e = __builtin_bit_cast(v8h, ev[tm][kk]);
            const v8h r = __builtin_bit_cast(v8h, rv[tm][kk]);
            const v8h af = __builtin_elementwise_max(e + r, zz);
            #pragma unroll
            for (int tn = 0; tn < 4; ++tn)
                a4[tn] = __builtin_amdgcn_mfma_f32_16x16x32_f16(af, bfr[kk][tn], a4[tn], 0, 0, 0);
        }
        #pragma unroll
        for (int i = 0; i < 4; ++i) {
            float s = 0.f;
            #pragma unroll
            for (int tn = 0; tn < 4; ++tn)
                s += fmaxf(a4[tn][i], 0.f) * w3v[tn];
            p[tm][i] = s;
        }
    }
    #pragma unroll
    for (int m = 1; m <= 8; m <<= 1)
        #pragma unroll
        for (int tm = 0; tm < 4; ++tm)
            #pragma unroll
            for (int i = 0; i < 4; ++i)
                p[tm][i] += __shfl_xor(p[tm][i], m);

    // ---- sigmoid -> exp -> softmax sum (logits in [0,1], no max-shift needed)
    float ee[4][4];
    float sloc = 0.f;
    #pragma unroll
    for (int tm = 0; tm < 4; ++tm)
        #pragma unroll
        for (int i = 0; i < 4; ++i) {
            const float sg = frcp(1.f + fexp(-p[tm][i]));
            const float ex = fexp(sg);
            ee[tm][i] = ex;
            sloc += ex;
        }
    sloc += __shfl_xor(sloc, 16);
    sloc += __shfl_xor(sloc, 32);
    const float rS = frcp(sloc);

    // wave-private weight exchange through LDS (same wave writes & reads: no barrier)
    if (q == 0) {
        #pragma unroll
        for (int tm = 0; tm < 4; ++tm) {
            v4f wv;
            #pragma unroll
            for (int i = 0; i < 4; ++i) wv[i] = ee[tm][i] * rS;
            *(v4f*)&ws_w[w][16 * tm + 4 * g] = wv;
        }
    }

    // ---- weighted t-sum + hop-0 means (packed f32 math)
    v2f a2[4], m2[4];
    #pragma unroll
    for (int c = 0; c < 4; ++c) { a2[c] = (v2f){0.f, 0.f}; m2[c] = (v2f){0.f, 0.f}; }
    #pragma unroll
    for (int it = 0; it < 8; ++it) {
        const float wg = ws_w[w][8 * it + grp];
        const v2f wv = (v2f){wg, wg};
        const v4u e = e0v[it];
        #pragma unroll
        for (int c = 0; c < 4; ++c) a2[c] += wv * up2(e[c]);
    }
    #pragma unroll
    for (int it = 0; it < 4; ++it) {
        const v4u e = m0v[it];
        #pragma unroll
        for (int c = 0; c < 4; ++c) m2[c] += up2(e[c]);
    }
    #pragma unroll
    for (int m = 8; m <= 32; m <<= 1)
        #pragma unroll
        for (int c = 0; c < 4; ++c) {
            a2[c][0] += __shfl_xor(a2[c][0], m);
            a2[c][1] += __shfl_xor(a2[c][1], m);
            m2[c][0] += __shfl_xor(m2[c][0], m);
            m2[c][1] += __shfl_xor(m2[c][1], m);
        }
    if (lane < 8) {
        #pragma unroll
        for (int c = 0; c < 4; ++c) {
            att_s[w][lane * 8 + 2 * c]     = a2[c][0];
            att_s[w][lane * 8 + 2 * c + 1] = a2[c][1];
            mp[w][lane * 8 + 2 * c]        = m2[c][0];
            mp[w][lane * 8 + 2 * c + 1]    = m2[c][1];
        }
    }
    __syncthreads();

    // ---- final combine + dot + sigmoid (wave 0 of each element)
    if (combo == 0) {
        const int j = lane;
        const int e4 = elem * 4;
        const float itemv = emb[(size_t)items[b] * 64 + j];
        const float eu = att_s[e4 + 0][j] + att_s[e4 + 1][j]
                       + (mp[e4 + 0][j] + mp[e4 + 1][j]) * (1.f / 64.f);
        const float evv = itemv + att_s[e4 + 2][j] + att_s[e4 + 3][j]
                       + (mp[e4 + 2][j] + mp[e4 + 3][j]) * (1.f / 64.f);
        float d = eu * evv;
        #pragma unroll
        for (int m = 1; m <= 32; m <<= 1) d += __shfl_xor(d, m);
        if (lane == 0) out[b] = frcp(1.f + fexp(-d));
    }
}

extern "C" void kernel_launch(void* const* d_in, const int* in_sizes, int n_in,
                              void* d_out, int out_size, void* d_ws, size_t ws_size,
                              hipStream_t stream)
{
    const int*   items  = (const int*)d_in[0];
    const int*   user_h = (const int*)d_in[1];
    const int*   user_r = (const int*)d_in[2];
    const int*   user_t = (const int*)d_in[3];
    const int*   item_h = (const int*)d_in[4];
    const int*   item_r = (const int*)d_in[5];
    const int*   item_t = (const int*)d_in[6];
    const float* emb    = (const float*)d_in[7];
    const float* rel    = (const float*)d_in[8];
    const float* W1     = (const float*)d_in[9];
    const float* W2     = (const float*)d_in[10];
    const float* W3     = (const float*)d_in[11];
    float* out = (float*)d_out;

    char* ws = (char*)d_ws;
    const size_t tb = (size_t)N_ENT * 64 * 2;            // 12.8 MB per table
    unsigned short* E0   = (unsigned short*)ws;
    unsigned short* E1h  = (unsigned short*)(ws + tb);
    unsigned short* R1h  = (unsigned short*)(ws + 2 * tb);
    unsigned short* W2ph = (unsigned short*)(ws + 2 * tb + 4096);
    unsigned short* W1p  = (unsigned short*)(ws + 2 * tb + 4096 + 8192);

    hipLaunchKernelGGL(k0_prep, dim3(36), dim3(256), 0, stream, rel, W1, W2, R1h, W2ph, W1p);
    hipLaunchKernelGGL(k1_e1, dim3((6250 + 3) / 4), dim3(256), 0, stream, emb, W1p, E1h, E0);
    hipLaunchKernelGGL(k2_fused, dim3(BATCH / 2), dim3(512), 0, stream,
                       items, user_h, user_r, user_t, item_h, item_r, item_t,
                       emb, E0, E1h, R1h, W2ph, W3, out);
}